// Round 1
// baseline (132.967 us; speedup 1.0000x reference)
//
#include <hip/hip_runtime.h>

// Problem: Bahdanau additive attention, S=T=512, DU=DT=512, D=1024, all fp32.
// ws layout (floats): A[512*1024] | B[512*1024] | scores[512*512] | weights[512*512]  = 6 MB

// ---------------- Kernel 1: A = rnn@W[:, :512].T ; B = tgt@W[:, 512:].T + b_lin ----
// Treated as one GEMM: C[i][j], i in [0,1024): i<512 -> A (in=rnn, koff=0),
// i>=512 -> B (in=tgt, koff=512, +bias). 64x64 tile, 256 thr, 4x4 micro.
__global__ __launch_bounds__(256) void k1_gemm_ab(
    const float* __restrict__ rnn, const float* __restrict__ tgt,
    const float* __restrict__ W, const float* __restrict__ bl,
    float* __restrict__ A, float* __restrict__ B)
{
    __shared__ float xt[16][68];   // [k][i] transposed
    __shared__ float wt[16][68];   // [k][j] transposed
    const int i0 = blockIdx.y * 64;
    const int j0 = blockIdx.x * 64;
    const bool isB = (i0 >= 512);
    const float* __restrict__ in = isB ? tgt : rnn;
    const int irow0 = isB ? (i0 - 512) : i0;
    const int koff = isB ? 512 : 0;
    const int tid = threadIdx.x;
    const int lrow = tid >> 2;     // 0..63
    const int kq   = tid & 3;      // float4 slot within 16-wide k chunk
    const int ti   = tid >> 4;     // 0..15
    const int tj   = tid & 15;     // 0..15
    float acc[4][4] = {};
    for (int k0 = 0; k0 < 512; k0 += 16) {
        const float4 xv = *(const float4*)(in + (size_t)(irow0 + lrow) * 512 + k0 + kq * 4);
        const float4 wv = *(const float4*)(W  + (size_t)(j0 + lrow) * 1024 + koff + k0 + kq * 4);
        __syncthreads();
        xt[kq*4+0][lrow] = xv.x; xt[kq*4+1][lrow] = xv.y;
        xt[kq*4+2][lrow] = xv.z; xt[kq*4+3][lrow] = xv.w;
        wt[kq*4+0][lrow] = wv.x; wt[kq*4+1][lrow] = wv.y;
        wt[kq*4+2][lrow] = wv.z; wt[kq*4+3][lrow] = wv.w;
        __syncthreads();
        #pragma unroll
        for (int k = 0; k < 16; ++k) {
            const float4 av = *(const float4*)&xt[k][ti * 4];
            const float4 bv = *(const float4*)&wt[k][tj * 4];
            const float ar[4] = {av.x, av.y, av.z, av.w};
            const float br[4] = {bv.x, bv.y, bv.z, bv.w};
            #pragma unroll
            for (int r = 0; r < 4; ++r)
                #pragma unroll
                for (int c = 0; c < 4; ++c)
                    acc[r][c] = __builtin_fmaf(ar[r], br[c], acc[r][c]);
        }
    }
    const int jj = j0 + tj * 4;
    float4 bias = make_float4(0.f, 0.f, 0.f, 0.f);
    if (isB) bias = *(const float4*)(bl + jj);
    float* __restrict__ dst = isB ? B : A;
    #pragma unroll
    for (int r = 0; r < 4; ++r) {
        const int lr = irow0 + ti * 4 + r;
        float4 o;
        o.x = acc[r][0] + bias.x; o.y = acc[r][1] + bias.y;
        o.z = acc[r][2] + bias.z; o.w = acc[r][3] + bias.w;
        *(float4*)(dst + (size_t)lr * 1024 + jj) = o;
    }
}

// ---------------- Kernel 2 (hot): scores[t][s] = b_s + sum_d w[d]*tanh(A[s,d]+B[t,d])
// 32x32 (t,s) tile per block, 256 thr (2x2 micro), d staged in 32-chunks (transposed LDS).
__global__ __launch_bounds__(256) void k2_scores(
    const float* __restrict__ A, const float* __restrict__ Bm,
    const float* __restrict__ wsc, const float* __restrict__ bsc,
    float* __restrict__ scores)
{
    __shared__ float at[32][36];   // [d][s]
    __shared__ float bt[32][36];   // [d][t]
    __shared__ float wl[1024];
    const int t0g = blockIdx.y * 32;
    const int s0g = blockIdx.x * 32;
    const int tid = threadIdx.x;
    for (int i = tid; i < 1024; i += 256) wl[i] = wsc[i];
    const int lrow = tid >> 3;         // 0..31
    const int q    = tid & 7;          // 0..7  (float4 slot over 32 d)
    const int tt   = (tid >> 4) * 2;   // local t base
    const int ss   = (tid & 15) * 2;   // local s base
    const float C2 = 2.8853900817779268f;  // 2*log2(e)
    float acc00 = 0.f, acc01 = 0.f, acc10 = 0.f, acc11 = 0.f;
    for (int d0 = 0; d0 < 1024; d0 += 32) {
        const float4 av = *(const float4*)(A  + (size_t)(s0g + lrow) * 1024 + d0 + q * 4);
        const float4 bv = *(const float4*)(Bm + (size_t)(t0g + lrow) * 1024 + d0 + q * 4);
        __syncthreads();
        at[q*4+0][lrow] = av.x; at[q*4+1][lrow] = av.y;
        at[q*4+2][lrow] = av.z; at[q*4+3][lrow] = av.w;
        bt[q*4+0][lrow] = bv.x; bt[q*4+1][lrow] = bv.y;
        bt[q*4+2][lrow] = bv.z; bt[q*4+3][lrow] = bv.w;
        __syncthreads();
        #pragma unroll
        for (int d = 0; d < 32; ++d) {
            const float w  = wl[d0 + d];
            const float a0 = at[d][ss], a1 = at[d][ss + 1];
            const float b0 = bt[d][tt], b1 = bt[d][tt + 1];
            const float bc0 = b0 * C2, bc1 = b1 * C2;
            float x, e, h;
            // tanh(x) = 1 - 2/(exp2(2*log2e*x)+1)
            x = __builtin_fmaf(a0, C2, bc0);
            e = __builtin_amdgcn_exp2f(x);
            h = __builtin_fmaf(-2.f, __builtin_amdgcn_rcpf(e + 1.f), 1.f);
            acc00 = __builtin_fmaf(w, h, acc00);
            x = __builtin_fmaf(a1, C2, bc0);
            e = __builtin_amdgcn_exp2f(x);
            h = __builtin_fmaf(-2.f, __builtin_amdgcn_rcpf(e + 1.f), 1.f);
            acc01 = __builtin_fmaf(w, h, acc01);
            x = __builtin_fmaf(a0, C2, bc1);
            e = __builtin_amdgcn_exp2f(x);
            h = __builtin_fmaf(-2.f, __builtin_amdgcn_rcpf(e + 1.f), 1.f);
            acc10 = __builtin_fmaf(w, h, acc10);
            x = __builtin_fmaf(a1, C2, bc1);
            e = __builtin_amdgcn_exp2f(x);
            h = __builtin_fmaf(-2.f, __builtin_amdgcn_rcpf(e + 1.f), 1.f);
            acc11 = __builtin_fmaf(w, h, acc11);
        }
    }
    const float bs = bsc[0];
    const int tg = t0g + tt, sg = s0g + ss;
    scores[(size_t)tg * 512 + sg]           = acc00 + bs;
    scores[(size_t)tg * 512 + sg + 1]       = acc01 + bs;
    scores[(size_t)(tg + 1) * 512 + sg]     = acc10 + bs;
    scores[(size_t)(tg + 1) * 512 + sg + 1] = acc11 + bs;
}

// ---------------- Kernel 3: row softmax over s --------------------------------------
__global__ __launch_bounds__(256) void k3_softmax(
    const float* __restrict__ scores, float* __restrict__ wgt)
{
    __shared__ float wm[4];
    __shared__ float wsum[4];
    const int t = blockIdx.x;
    const int tid = threadIdx.x;
    const float2 v = *(const float2*)(scores + (size_t)t * 512 + tid * 2);
    float m = fmaxf(v.x, v.y);
    #pragma unroll
    for (int off = 32; off; off >>= 1) m = fmaxf(m, __shfl_xor(m, off));
    if ((tid & 63) == 0) wm[tid >> 6] = m;
    __syncthreads();
    m = fmaxf(fmaxf(wm[0], wm[1]), fmaxf(wm[2], wm[3]));
    const float L2E = 1.4426950408889634f;
    const float e0 = __builtin_amdgcn_exp2f((v.x - m) * L2E);
    const float e1 = __builtin_amdgcn_exp2f((v.y - m) * L2E);
    float s = e0 + e1;
    #pragma unroll
    for (int off = 32; off; off >>= 1) s += __shfl_xor(s, off);
    if ((tid & 63) == 0) wsum[tid >> 6] = s;
    __syncthreads();
    s = wsum[0] + wsum[1] + wsum[2] + wsum[3];
    const float inv = 1.0f / s;
    float2 o; o.x = e0 * inv; o.y = e1 * inv;
    *(float2*)(wgt + (size_t)t * 512 + tid * 2) = o;
}

// ---------------- Kernel 4: out = weights @ rnn  (M=T=512, N=DU=512, K=S=512) -------
__global__ __launch_bounds__(256) void k4_out(
    const float* __restrict__ wgt, const float* __restrict__ rnn,
    float* __restrict__ out)
{
    __shared__ float wt_t[32][36];  // [s][t]
    __shared__ float rn[32][36];    // [s][d]
    const int t0 = blockIdx.y * 32;
    const int d0 = blockIdx.x * 32;
    const int tid = threadIdx.x;
    const int lrow = tid >> 3;       // 0..31
    const int q    = tid & 7;        // 0..7
    const int tt   = (tid >> 4) * 2;
    const int dd   = (tid & 15) * 2;
    float a00 = 0.f, a01 = 0.f, a10 = 0.f, a11 = 0.f;
    for (int s0 = 0; s0 < 512; s0 += 32) {
        const float4 wv = *(const float4*)(wgt + (size_t)(t0 + lrow) * 512 + s0 + q * 4);
        const float4 rv = *(const float4*)(rnn + (size_t)(s0 + lrow) * 512 + d0 + q * 4);
        __syncthreads();
        wt_t[q*4+0][lrow] = wv.x; wt_t[q*4+1][lrow] = wv.y;
        wt_t[q*4+2][lrow] = wv.z; wt_t[q*4+3][lrow] = wv.w;
        rn[lrow][q*4+0] = rv.x; rn[lrow][q*4+1] = rv.y;
        rn[lrow][q*4+2] = rv.z; rn[lrow][q*4+3] = rv.w;
        __syncthreads();
        #pragma unroll
        for (int s = 0; s < 32; ++s) {
            const float w0 = wt_t[s][tt], w1 = wt_t[s][tt + 1];
            const float r0 = rn[s][dd],   r1 = rn[s][dd + 1];
            a00 = __builtin_fmaf(w0, r0, a00);
            a01 = __builtin_fmaf(w0, r1, a01);
            a10 = __builtin_fmaf(w1, r0, a10);
            a11 = __builtin_fmaf(w1, r1, a11);
        }
    }
    out[(size_t)(t0 + tt) * 512 + d0 + dd]           = a00;
    out[(size_t)(t0 + tt) * 512 + d0 + dd + 1]       = a01;
    out[(size_t)(t0 + tt + 1) * 512 + d0 + dd]       = a10;
    out[(size_t)(t0 + tt + 1) * 512 + d0 + dd + 1]   = a11;
}

extern "C" void kernel_launch(void* const* d_in, const int* in_sizes, int n_in,
                              void* d_out, int out_size, void* d_ws, size_t ws_size,
                              hipStream_t stream) {
    const float* rnn = (const float*)d_in[0];   // [512,512]
    const float* tgt = (const float*)d_in[1];   // [512,512]
    const float* W   = (const float*)d_in[2];   // [1024,1024]
    const float* bl  = (const float*)d_in[3];   // [1024]
    const float* wsc = (const float*)d_in[4];   // [1024]
    const float* bsc = (const float*)d_in[5];   // [1]
    float* out = (float*)d_out;                 // [512,512] fp32

    float* A      = (float*)d_ws;               // 512*1024
    float* B      = A + 512 * 1024;             // 512*1024
    float* scores = B + 512 * 1024;             // 512*512
    float* wgt    = scores + 512 * 512;         // 512*512

    k1_gemm_ab<<<dim3(16, 16), 256, 0, stream>>>(rnn, tgt, W, bl, A, B);
    k2_scores <<<dim3(16, 16), 256, 0, stream>>>(A, B, wsc, bsc, scores);
    k3_softmax<<<512, 256, 0, stream>>>(scores, wgt);
    k4_out    <<<dim3(16, 16), 256, 0, stream>>>(wgt, rnn, out);
}

// Round 2
// 117.753 us; speedup vs baseline: 1.1292x; 1.1292x over previous
//
#include <hip/hip_runtime.h>

// Bahdanau additive attention, S=T=512, DU=DT=512, D=1024, fp32.
// score[t,s] = b_s + sum_d w[d]*tanh(A[s,d]+B[t,d]);  out = softmax_s(score) @ rnn
// Identity used: tanh(x) = 1 - 2/(exp(2x)+1)  ->  score = (b_s + sum_w) - 2*sum_d w*rcp(exp2(C2*(a+b))+1)
// softmax is shift-invariant => (b_s + sum_w) drops; C2=2*log2(e) is folded into A,B at k1 epilogue.
// ws (floats): A[512*1024] | B[512*1024] | P[4][512*512] | wgt[512*512]  ~= 9.2 MB

#define C2F 2.8853900817779268f   // 2*log2(e)

// ---- k1: A = (rnn @ W[:, :512].T) * C2 ; B = (tgt @ W[:, 512:].T + b_lin) * C2 ----
// One logical GEMM over i in [0,1024): i<512 -> A, i>=512 -> B. 32x32 tile, 2x2 micro.
__global__ __launch_bounds__(256, 4) void k1_gemm_ab(
    const float* __restrict__ rnn, const float* __restrict__ tgt,
    const float* __restrict__ W, const float* __restrict__ bl,
    float* __restrict__ A, float* __restrict__ B)
{
    __shared__ float xt[64][34];   // [k][i]
    __shared__ float wt[64][34];   // [k][j]
    const int j0 = blockIdx.x * 32;           // 0..1023
    const int i0 = blockIdx.y * 32;           // 0..1023
    const bool isB = (i0 >= 512);
    const float* __restrict__ in = isB ? tgt : rnn;
    const int irow0 = isB ? (i0 - 512) : i0;
    const int koff = isB ? 512 : 0;
    const int tid = threadIdx.x;
    const int lrow = tid >> 3;                // 0..31
    const int q    = tid & 7;                 // 0..7
    const int ii   = (tid & 15) * 2;          // local i
    const int jj   = (tid >> 4) * 2;          // local j
    float a00 = 0.f, a01 = 0.f, a10 = 0.f, a11 = 0.f;
    for (int k0 = 0; k0 < 512; k0 += 64) {
        const float4 x0 = *(const float4*)(in + (size_t)(irow0 + lrow) * 512 + k0 + q * 8);
        const float4 x1 = *(const float4*)(in + (size_t)(irow0 + lrow) * 512 + k0 + q * 8 + 4);
        const float4 w0 = *(const float4*)(W + (size_t)(j0 + lrow) * 1024 + koff + k0 + q * 8);
        const float4 w1 = *(const float4*)(W + (size_t)(j0 + lrow) * 1024 + koff + k0 + q * 8 + 4);
        __syncthreads();
        xt[q*8+0][lrow] = x0.x; xt[q*8+1][lrow] = x0.y; xt[q*8+2][lrow] = x0.z; xt[q*8+3][lrow] = x0.w;
        xt[q*8+4][lrow] = x1.x; xt[q*8+5][lrow] = x1.y; xt[q*8+6][lrow] = x1.z; xt[q*8+7][lrow] = x1.w;
        wt[q*8+0][lrow] = w0.x; wt[q*8+1][lrow] = w0.y; wt[q*8+2][lrow] = w0.z; wt[q*8+3][lrow] = w0.w;
        wt[q*8+4][lrow] = w1.x; wt[q*8+5][lrow] = w1.y; wt[q*8+6][lrow] = w1.z; wt[q*8+7][lrow] = w1.w;
        __syncthreads();
        #pragma unroll
        for (int k = 0; k < 64; ++k) {
            const float2 av = *(const float2*)&xt[k][ii];
            const float2 bv = *(const float2*)&wt[k][jj];
            a00 = __builtin_fmaf(av.x, bv.x, a00);
            a01 = __builtin_fmaf(av.x, bv.y, a01);
            a10 = __builtin_fmaf(av.y, bv.x, a10);
            a11 = __builtin_fmaf(av.y, bv.y, a11);
        }
    }
    float b0 = 0.f, b1 = 0.f;
    if (isB) { b0 = bl[j0 + jj]; b1 = bl[j0 + jj + 1]; }
    float* __restrict__ dst = isB ? B : A;
    float2 o0, o1;
    o0.x = (a00 + b0) * C2F; o0.y = (a01 + b1) * C2F;
    o1.x = (a10 + b0) * C2F; o1.y = (a11 + b1) * C2F;
    *(float2*)(dst + (size_t)(irow0 + ii) * 1024 + j0 + jj)     = o0;
    *(float2*)(dst + (size_t)(irow0 + ii + 1) * 1024 + j0 + jj) = o1;
}

// ---- k2 (hot): P[z][t][s] = sum_{d in chunk z} w[d] * rcp(exp2(a+b)+1) ----
// 32x32 (t,s) tile, 2x2 micro, d split 4 ways via blockIdx.z -> 1024 blocks.
__global__ __launch_bounds__(256, 4) void k2_scores(
    const float* __restrict__ A, const float* __restrict__ Bm,
    const float* __restrict__ wsc, float* __restrict__ P)
{
    __shared__ float at[32][34];   // [d][s]
    __shared__ float bt[32][34];   // [d][t]
    __shared__ float wl[256];
    const int s0 = blockIdx.x * 32;
    const int t0 = blockIdx.y * 32;
    const int dz = blockIdx.z * 256;
    const int tid = threadIdx.x;
    wl[tid] = wsc[dz + tid];
    const int lrow = tid >> 3;          // 0..31
    const int q    = tid & 7;           // 0..7
    const int ss   = (tid & 15) * 2;
    const int tt   = (tid >> 4) * 2;
    float acc00 = 0.f, acc01 = 0.f, acc10 = 0.f, acc11 = 0.f;
    for (int d0 = 0; d0 < 256; d0 += 32) {
        const float4 av = *(const float4*)(A  + (size_t)(s0 + lrow) * 1024 + dz + d0 + q * 4);
        const float4 bv = *(const float4*)(Bm + (size_t)(t0 + lrow) * 1024 + dz + d0 + q * 4);
        __syncthreads();
        at[q*4+0][lrow] = av.x; at[q*4+1][lrow] = av.y;
        at[q*4+2][lrow] = av.z; at[q*4+3][lrow] = av.w;
        bt[q*4+0][lrow] = bv.x; bt[q*4+1][lrow] = bv.y;
        bt[q*4+2][lrow] = bv.z; bt[q*4+3][lrow] = bv.w;
        __syncthreads();
        #pragma unroll
        for (int d = 0; d < 32; ++d) {
            const float w = wl[d0 + d];
            const float2 a = *(const float2*)&at[d][ss];
            const float2 b = *(const float2*)&bt[d][tt];
            float x, r;
            x = a.x + b.x;
            r = __builtin_amdgcn_rcpf(__builtin_amdgcn_exp2f(x) + 1.f);
            acc00 = __builtin_fmaf(w, r, acc00);
            x = a.y + b.x;
            r = __builtin_amdgcn_rcpf(__builtin_amdgcn_exp2f(x) + 1.f);
            acc01 = __builtin_fmaf(w, r, acc01);
            x = a.x + b.y;
            r = __builtin_amdgcn_rcpf(__builtin_amdgcn_exp2f(x) + 1.f);
            acc10 = __builtin_fmaf(w, r, acc10);
            x = a.y + b.y;
            r = __builtin_amdgcn_rcpf(__builtin_amdgcn_exp2f(x) + 1.f);
            acc11 = __builtin_fmaf(w, r, acc11);
        }
    }
    float* __restrict__ Pz = P + (size_t)blockIdx.z * 512 * 512;
    float2 o0, o1;
    o0.x = acc00; o0.y = acc01;
    o1.x = acc10; o1.y = acc11;
    *(float2*)(Pz + (size_t)(t0 + tt) * 512 + s0 + ss)     = o0;
    *(float2*)(Pz + (size_t)(t0 + tt + 1) * 512 + s0 + ss) = o1;
}

// ---- k3: weights[t][:] = softmax_s( -2 * (P0+P1+P2+P3)[t][:] ) ----
__global__ __launch_bounds__(256, 4) void k3_softmax(
    const float* __restrict__ P, float* __restrict__ wgt)
{
    __shared__ float wm[4];
    __shared__ float wsum[4];
    const int t = blockIdx.x;
    const int tid = threadIdx.x;
    const size_t base = (size_t)t * 512 + tid * 2;
    const float2 p0 = *(const float2*)(P + base);
    const float2 p1 = *(const float2*)(P + base + 262144);
    const float2 p2 = *(const float2*)(P + base + 2 * 262144);
    const float2 p3 = *(const float2*)(P + base + 3 * 262144);
    const float x0 = -2.f * (p0.x + p1.x + p2.x + p3.x);
    const float x1 = -2.f * (p0.y + p1.y + p2.y + p3.y);
    float m = fmaxf(x0, x1);
    #pragma unroll
    for (int off = 32; off; off >>= 1) m = fmaxf(m, __shfl_xor(m, off));
    if ((tid & 63) == 0) wm[tid >> 6] = m;
    __syncthreads();
    m = fmaxf(fmaxf(wm[0], wm[1]), fmaxf(wm[2], wm[3]));
    const float L2E = 1.4426950408889634f;
    const float e0 = __builtin_amdgcn_exp2f((x0 - m) * L2E);
    const float e1 = __builtin_amdgcn_exp2f((x1 - m) * L2E);
    float s = e0 + e1;
    #pragma unroll
    for (int off = 32; off; off >>= 1) s += __shfl_xor(s, off);
    if ((tid & 63) == 0) wsum[tid >> 6] = s;
    __syncthreads();
    s = wsum[0] + wsum[1] + wsum[2] + wsum[3];
    const float inv = 1.0f / s;
    float2 o; o.x = e0 * inv; o.y = e1 * inv;
    *(float2*)(wgt + (size_t)t * 512 + tid * 2) = o;
}

// ---- k4: out = weights @ rnn  (M=T=512, N=DU=512, K=S=512) ----
__global__ __launch_bounds__(256) void k4_out(
    const float* __restrict__ wgt, const float* __restrict__ rnn,
    float* __restrict__ out)
{
    __shared__ float wt_t[32][36];  // [s][t]
    __shared__ float rn[32][36];    // [s][d]
    const int t0 = blockIdx.y * 32;
    const int d0 = blockIdx.x * 32;
    const int tid = threadIdx.x;
    const int lrow = tid >> 3;
    const int q    = tid & 7;
    const int tt   = (tid >> 4) * 2;
    const int dd   = (tid & 15) * 2;
    float a00 = 0.f, a01 = 0.f, a10 = 0.f, a11 = 0.f;
    for (int s0 = 0; s0 < 512; s0 += 32) {
        const float4 wv = *(const float4*)(wgt + (size_t)(t0 + lrow) * 512 + s0 + q * 4);
        const float4 rv = *(const float4*)(rnn + (size_t)(s0 + lrow) * 512 + d0 + q * 4);
        __syncthreads();
        wt_t[q*4+0][lrow] = wv.x; wt_t[q*4+1][lrow] = wv.y;
        wt_t[q*4+2][lrow] = wv.z; wt_t[q*4+3][lrow] = wv.w;
        rn[lrow][q*4+0] = rv.x; rn[lrow][q*4+1] = rv.y;
        rn[lrow][q*4+2] = rv.z; rn[lrow][q*4+3] = rv.w;
        __syncthreads();
        #pragma unroll
        for (int s = 0; s < 32; ++s) {
            const float w0 = wt_t[s][tt], w1 = wt_t[s][tt + 1];
            const float r0 = rn[s][dd],   r1 = rn[s][dd + 1];
            a00 = __builtin_fmaf(w0, r0, a00);
            a01 = __builtin_fmaf(w0, r1, a01);
            a10 = __builtin_fmaf(w1, r0, a10);
            a11 = __builtin_fmaf(w1, r1, a11);
        }
    }
    out[(size_t)(t0 + tt) * 512 + d0 + dd]           = a00;
    out[(size_t)(t0 + tt) * 512 + d0 + dd + 1]       = a01;
    out[(size_t)(t0 + tt + 1) * 512 + d0 + dd]       = a10;
    out[(size_t)(t0 + tt + 1) * 512 + d0 + dd + 1]   = a11;
}

extern "C" void kernel_launch(void* const* d_in, const int* in_sizes, int n_in,
                              void* d_out, int out_size, void* d_ws, size_t ws_size,
                              hipStream_t stream) {
    const float* rnn = (const float*)d_in[0];   // [512,512]
    const float* tgt = (const float*)d_in[1];   // [512,512]
    const float* W   = (const float*)d_in[2];   // [1024,1024]
    const float* bl  = (const float*)d_in[3];   // [1024]
    const float* wsc = (const float*)d_in[4];   // [1024]
    // d_in[5] (b_score) is a constant shift under softmax -> unused.
    float* out = (float*)d_out;                 // [512,512] fp32

    float* A   = (float*)d_ws;                  // 512*1024
    float* B   = A + 512 * 1024;                // 512*1024
    float* P   = B + 512 * 1024;                // 4 * 512*512 partials
    float* wgt = P + 4 * 512 * 512;             // 512*512

    k1_gemm_ab<<<dim3(32, 32),    256, 0, stream>>>(rnn, tgt, W, bl, A, B);
    k2_scores <<<dim3(16, 16, 4), 256, 0, stream>>>(A, B, wsc, P);
    k3_softmax<<<512,             256, 0, stream>>>(P, wgt);
    k4_out    <<<dim3(16, 16),    256, 0, stream>>>(wgt, rnn, out);
}